// Round 3
// baseline (1531.939 us; speedup 1.0000x reference)
//
#include <hip/hip_runtime.h>

// MyRNNCell, two-pass MFMA design.
//
//   Wh = W[0:256], Wx = W[256:384];  h_{t+1} = tanh(h_t @ Wh + xp_t),
//   xp = x @ Wx + bias  (precomputed, full-chip).
//
// Pass 1 (xproj_kernel, 2048 wgs): xp[b,t,u] as f16, stored PRE-PACKED in the
// scan's per-lane C-fragment order: lane slot j=nt*4+r holds
// xp[b0+4*quad+r][t][64*wv+16*nt+l15]. Scan reads 32 B/lane/step, no relayout.
//
// Pass 2 (scan_kernel, 16 wgs = B/16, the batch-MFMA cap): per step
//   8x ds_read_b128 A-frags (h only, K=256) -> 32 mfma_f32_16x16x32_f16
//   (acc init = xp fragment) -> tanh -> f16 publish to LDS[nxt] -> barrier ->
//   f32 global stores AFTER the barrier (ack drains at the NEXT barrier,
//   one full step of slack -> store latency off the critical path).
// xp prefetched 2 steps ahead. One barrier per step.
//
// Fallback: if ws_size < 128 MB the round-2 single-kernel version runs.

typedef _Float16 half8 __attribute__((ext_vector_type(8)));
typedef float floatx4 __attribute__((ext_vector_type(4)));

constexpr int B = 256, T = 1024, D = 128, U = 256;
constexpr int QS  = 16 * 16 + 16;   // 272 B quad stride (+16 pad)
constexpr int SS  = 4 * QS;         // 1088 B slice stride (32 k-values)
constexpr int HSL = U / 32;         // 8 h-slices (scan K)
constexpr int XSL = D / 32;         // 4 x-slices (pass-1 K)
constexpr int HBUF = HSL * SS;      // 8704 B per h A-buffer
constexpr int TC  = 8;              // t-steps per pass-1 workgroup
constexpr size_t XP_BYTES = (size_t)B * T * U * 2;   // 128 MB f16

__device__ __forceinline__ float fast_tanh(float v) {
    // tanh(v) = 1 - 2/(e^{2v}+1); exp2->inf, rcp(inf)=0 saturate exactly.
    float e = __builtin_exp2f(2.8853900817779268f * v);
    return 1.0f - 2.0f * __builtin_amdgcn_rcpf(e + 1.0f);
}

__device__ __forceinline__ void cvt_write8(void* dst, float4 lo, float4 hi) {
    half8 h;
    h[0] = (_Float16)lo.x; h[1] = (_Float16)lo.y;
    h[2] = (_Float16)lo.z; h[3] = (_Float16)lo.w;
    h[4] = (_Float16)hi.x; h[5] = (_Float16)hi.y;
    h[6] = (_Float16)hi.z; h[7] = (_Float16)hi.w;
    *reinterpret_cast<half8*>(dst) = h;
}

// ---------------- Pass 1: xp = x @ Wx + bias, f16, lane-fragment order -----
__global__ __launch_bounds__(256, 2)
void xproj_kernel(const float* __restrict__ x, const float* __restrict__ W,
                  const float* __restrict__ bias, _Float16* __restrict__ xp)
{
    __shared__ __align__(16) unsigned char lds[TC * XSL * SS];   // 34816 B

    const int tid  = threadIdx.x;
    const int lane = tid & 63, wv = tid >> 6;
    const int l15  = lane & 15, quad = lane >> 4;
    const int g    = blockIdx.x & 15;         // batch group
    const int t0   = (blockIdx.x >> 4) * TC;  // t-chunk base
    const int b0   = g * 16;

    // stage x[b0..b0+15][t0..t0+7][0..127] as f16 A-layout, all 8 t upfront
    const int sm = tid >> 4, sc = tid & 15;   // batch row / d-chunk of 8
#pragma unroll
    for (int tt = 0; tt < TC; ++tt) {
        const float* xr = x + ((size_t)(b0 + sm) * T + (t0 + tt)) * D + 8 * sc;
        cvt_write8(lds + tt * (XSL * SS) + (sc >> 2) * SS + (sc & 3) * QS + sm * 16,
                   *reinterpret_cast<const float4*>(xr),
                   *reinterpret_cast<const float4*>(xr + 4));
    }

    // Wx fragments (B operand) + bias
    half8 wxf[4][XSL];
    float bv[4];
#pragma unroll
    for (int nt = 0; nt < 4; ++nt) {
        const int n = 64 * wv + 16 * nt + l15;
        bv[nt] = bias[n];
#pragma unroll
        for (int s = 0; s < XSL; ++s) {
            half8 f;
#pragma unroll
            for (int j = 0; j < 8; ++j)
                f[j] = (_Float16)W[(size_t)(U + 32 * s + 8 * quad + j) * U + n];
            wxf[nt][s] = f;
        }
    }
    __syncthreads();

#pragma unroll 2
    for (int tt = 0; tt < TC; ++tt) {
        half8 a[XSL];
        const unsigned char* ab = lds + tt * (XSL * SS) + quad * QS + l15 * 16;
#pragma unroll
        for (int s = 0; s < XSL; ++s)
            a[s] = *reinterpret_cast<const half8*>(ab + s * SS);

        floatx4 acc[4];
#pragma unroll
        for (int nt = 0; nt < 4; ++nt)
            acc[nt] = (floatx4){bv[nt], bv[nt], bv[nt], bv[nt]};
#pragma unroll
        for (int s = 0; s < XSL; ++s)
#pragma unroll
            for (int nt = 0; nt < 4; ++nt)
                acc[nt] = __builtin_amdgcn_mfma_f32_16x16x32_f16(
                              a[s], wxf[nt][s], acc[nt], 0, 0, 0);

        // pack lane's 16 values (j = nt*4 + r) and store 32 B contiguous
        half8 o0, o1;
#pragma unroll
        for (int r = 0; r < 4; ++r) {
            o0[r]     = (_Float16)acc[0][r];
            o0[4 + r] = (_Float16)acc[1][r];
            o1[r]     = (_Float16)acc[2][r];
            o1[4 + r] = (_Float16)acc[3][r];
        }
        _Float16* dst = xp + (((size_t)g * T + t0 + tt) * 256 + wv * 64 + lane) * 16;
        *reinterpret_cast<half8*>(dst)     = o0;
        *reinterpret_cast<half8*>(dst + 8) = o1;
    }
}

// ---------------- Pass 2: the scan --------------------------------------
__global__ __launch_bounds__(256, 1)
void scan_kernel(const float* __restrict__ h0, const float* __restrict__ W,
                 const _Float16* __restrict__ xp, float* __restrict__ out)
{
    __shared__ __align__(16) unsigned char lds[2 * HBUF];

    const int tid  = threadIdx.x;
    const int lane = tid & 63, wv = tid >> 6;
    const int l15  = lane & 15, quad = lane >> 4;
    const int g    = blockIdx.x;
    const int b0   = g * 16;

    // Wh fragments (B operand), 128 VGPRs
    half8 whf[4][HSL];
#pragma unroll
    for (int nt = 0; nt < 4; ++nt) {
        const int n = 64 * wv + 16 * nt + l15;
#pragma unroll
        for (int s = 0; s < HSL; ++s) {
            half8 f;
#pragma unroll
            for (int j = 0; j < 8; ++j)
                f[j] = (_Float16)W[(size_t)(32 * s + 8 * quad + j) * U + n];
            whf[nt][s] = f;
        }
    }

    // h0 -> buffer 0 (A-layout f16)
    const int sm = tid >> 4, sc = tid & 15;
#pragma unroll
    for (int cc = sc; cc < 32; cc += 16) {
        const float* hp = h0 + (size_t)(b0 + sm) * U + 8 * cc;
        cvt_write8(lds + (cc >> 2) * SS + (cc & 3) * QS + sm * 16,
                   *reinterpret_cast<const float4*>(hp),
                   *reinterpret_cast<const float4*>(hp + 4));
    }

    // xp per-lane stream: 32 B per step
    const _Float16* xl = xp + ((size_t)g * T * 256 + wv * 64 + lane) * 16;
    half8 c0 = *reinterpret_cast<const half8*>(xl);           // t = 0
    half8 c1 = *reinterpret_cast<const half8*>(xl + 8);
    half8 n0 = *reinterpret_cast<const half8*>(xl + 4096);    // t = 1
    half8 n1 = *reinterpret_cast<const half8*>(xl + 4096 + 8);

    __syncthreads();

    for (int t = 0; t < T; ++t) {
        const int cur = t & 1, nxt = cur ^ 1;

        // prefetch xp for t+2 (drains at next barrier; L3-resident)
        const size_t tp = (size_t)((t + 2 < T) ? t + 2 : T - 1) * 4096;
        half8 q0 = *reinterpret_cast<const half8*>(xl + tp);
        half8 q1 = *reinterpret_cast<const half8*>(xl + tp + 8);

        // A fragments (h_t)
        half8 a[HSL];
        const unsigned char* ab = lds + cur * HBUF + quad * QS + l15 * 16;
#pragma unroll
        for (int s = 0; s < HSL; ++s)
            a[s] = *reinterpret_cast<const half8*>(ab + s * SS);

        // acc init = xp fragment (bias already folded in)
        floatx4 acc[4];
#pragma unroll
        for (int r = 0; r < 4; ++r) {
            acc[0][r] = (float)c0[r];
            acc[1][r] = (float)c0[4 + r];
            acc[2][r] = (float)c1[r];
            acc[3][r] = (float)c1[4 + r];
        }
#pragma unroll
        for (int s = 0; s < HSL; ++s)
#pragma unroll
            for (int nt = 0; nt < 4; ++nt)
                acc[nt] = __builtin_amdgcn_mfma_f32_16x16x32_f16(
                              a[s], whf[nt][s], acc[nt], 0, 0, 0);

        // epilogue: tanh, publish f16 h to LDS[nxt], keep f32 for post-barrier store
        float hold[16];
        unsigned char* hb = lds + nxt * HBUF;
#pragma unroll
        for (int nt = 0; nt < 4; ++nt) {
            const int n = 64 * wv + 16 * nt + l15;
#pragma unroll
            for (int r = 0; r < 4; ++r) {
                const int m = 4 * quad + r;
                const float h = fast_tanh(acc[nt][r]);
                hold[nt * 4 + r] = h;
                *reinterpret_cast<_Float16*>(
                    hb + (n >> 5) * SS + ((n >> 3) & 3) * QS + m * 16 + (n & 7) * 2)
                    = (_Float16)h;
            }
        }
        c0 = n0; c1 = n1; n0 = q0; n1 = q1;

        __syncthreads();

        // f32 output stores AFTER the barrier: ack drains at the NEXT barrier
#pragma unroll
        for (int nt = 0; nt < 4; ++nt) {
            const int n = 64 * wv + 16 * nt + l15;
#pragma unroll
            for (int r = 0; r < 4; ++r)
                out[((size_t)(b0 + 4 * quad + r) * T + t) * U + n] = hold[nt * 4 + r];
        }
    }
}

// ---------------- Fallback (round-2 kernel) if ws is too small -----------
constexpr int NSL = (U + D) / 32;
constexpr int BUF = NSL * SS;

__global__ __launch_bounds__(256, 1)
void rnn_mfma_kernel(const float* __restrict__ x, const float* __restrict__ h0,
                     const float* __restrict__ W, const float* __restrict__ bias,
                     float* __restrict__ out)
{
    __shared__ __align__(16) unsigned char lds[2 * BUF];
    const int tid  = threadIdx.x;
    const int lane = tid & 63, wv = tid >> 6;
    const int l15  = lane & 15, quad = lane >> 4;
    const int b0   = blockIdx.x * 16;

    half8 wf[4][NSL];
    float bv[4];
#pragma unroll
    for (int nt = 0; nt < 4; ++nt) {
        const int n = 64 * wv + 16 * nt + l15;
        bv[nt] = bias[n];
#pragma unroll
        for (int s = 0; s < NSL; ++s) {
            half8 f;
#pragma unroll
            for (int j = 0; j < 8; ++j)
                f[j] = (_Float16)W[(size_t)(32 * s + 8 * quad + j) * U + n];
            wf[nt][s] = f;
        }
    }

    const int sm = tid >> 4, sc = tid & 15;
#pragma unroll
    for (int cc = sc; cc < 32; cc += 16) {
        const float* hp = h0 + (size_t)(b0 + sm) * U + 8 * cc;
        cvt_write8(lds + (cc >> 2) * SS + (cc & 3) * QS + sm * 16,
                   *reinterpret_cast<const float4*>(hp),
                   *reinterpret_cast<const float4*>(hp + 4));
    }
    const float* xbase = x + (size_t)(b0 + sm) * T * D + 8 * sc;
    cvt_write8(lds + (8 + (sc >> 2)) * SS + (sc & 3) * QS + sm * 16,
               *reinterpret_cast<const float4*>(xbase),
               *reinterpret_cast<const float4*>(xbase + 4));
    float4 p0 = *reinterpret_cast<const float4*>(xbase + D);
    float4 p1 = *reinterpret_cast<const float4*>(xbase + D + 4);
    __syncthreads();

    for (int t = 0; t < T; ++t) {
        const int cur = t & 1, nxt = cur ^ 1;
        const int tp = (t + 2 < T) ? (t + 2) : (T - 1);
        float4 q0 = *reinterpret_cast<const float4*>(xbase + (size_t)D * tp);
        float4 q1 = *reinterpret_cast<const float4*>(xbase + (size_t)D * tp + 4);

        half8 a[NSL];
        const unsigned char* ab = lds + cur * BUF + quad * QS + l15 * 16;
#pragma unroll
        for (int s = 0; s < NSL; ++s)
            a[s] = *reinterpret_cast<const half8*>(ab + s * SS);

        floatx4 acc[4];
#pragma unroll
        for (int nt = 0; nt < 4; ++nt)
            acc[nt] = (floatx4){bv[nt], bv[nt], bv[nt], bv[nt]};
#pragma unroll
        for (int s = 0; s < NSL; ++s)
#pragma unroll
            for (int nt = 0; nt < 4; ++nt)
                acc[nt] = __builtin_amdgcn_mfma_f32_16x16x32_f16(
                              a[s], wf[nt][s], acc[nt], 0, 0, 0);

        unsigned char* hb = lds + nxt * BUF;
#pragma unroll
        for (int nt = 0; nt < 4; ++nt) {
            const int n = 64 * wv + 16 * nt + l15;
#pragma unroll
            for (int r = 0; r < 4; ++r) {
                const int m = 4 * quad + r;
                const float h = fast_tanh(acc[nt][r]);
                out[((size_t)(b0 + m) * T + t) * U + n] = h;
                *reinterpret_cast<_Float16*>(
                    hb + (n >> 5) * SS + ((n >> 3) & 3) * QS + m * 16 + (n & 7) * 2)
                    = (_Float16)h;
            }
        }
        cvt_write8(hb + (8 + (sc >> 2)) * SS + (sc & 3) * QS + sm * 16, p0, p1);
        p0 = q0; p1 = q1;
        __syncthreads();
    }
}

extern "C" void kernel_launch(void* const* d_in, const int* in_sizes, int n_in,
                              void* d_out, int out_size, void* d_ws, size_t ws_size,
                              hipStream_t stream) {
    const float* x    = (const float*)d_in[0];
    const float* h0   = (const float*)d_in[1];
    const float* W    = (const float*)d_in[2];
    const float* bias = (const float*)d_in[3];
    float* out = (float*)d_out;

    if (ws_size >= XP_BYTES) {
        _Float16* xp = (_Float16*)d_ws;
        hipLaunchKernelGGL(xproj_kernel, dim3(16 * (T / TC)), dim3(256), 0, stream,
                           x, W, bias, xp);
        hipLaunchKernelGGL(scan_kernel, dim3(B / 16), dim3(256), 0, stream,
                           h0, W, xp, out);
    } else {
        hipLaunchKernelGGL(rnn_mfma_kernel, dim3(B / 16), dim3(256), 0, stream,
                           x, h0, W, bias, out);
    }
}